// Round 8
// baseline (4583.480 us; speedup 1.0000x reference)
//
#include <hip/hip_runtime.h>

// SimpleRNN: B=64,T=512,I=128,H=1024,L=4,O=128
// Round 8: r7 dedicated-role fused kernel with
//  (a) rec geometry 128 blocks: 4 layers x 4 bg(16 batches) x 8 members
//      (128 neurons) -> per-block h ingest 32 KB/step (was 64 KB),
//  (b) all GEMM operands pre-converted to bf16 planes (x hi/lo, Wih0 hi/lo,
//      WihL hi, Wfc hi/lo) -> tile staging is pure 16B copies,
//  (c) GEMM roles: l0=32 blocks, l1..3=24 each, FC=8; grid 240.
#define B_ 64
#define T_ 512
#define I_ 128
#define H_ 1024
#define L_ 4
#define O_ 128
#define M_ (B_ * T_)
#define S_ 16               // chunk steps
#define NCH 32              // T_/S_
#define ROWS 1024           // S_*B_ rows per chunk

typedef __attribute__((ext_vector_type(8))) short bf16x8_t;
typedef __attribute__((ext_vector_type(4))) float f32x4_t;

__device__ __forceinline__ unsigned short f2bf(float v) {
  unsigned int u = __builtin_bit_cast(unsigned int, v);
  u += 0x7FFFu + ((u >> 16) & 1u);
  return (unsigned short)(u >> 16);
}
__device__ __forceinline__ float bf2f(unsigned short h) {
  return __builtin_bit_cast(float, ((unsigned int)h) << 16);
}
__device__ __forceinline__ f32x4_t mfma16(bf16x8_t a, bf16x8_t b, f32x4_t c) {
  return __builtin_amdgcn_mfma_f32_16x16x32_bf16(a, b, c, 0, 0, 0);
}
__device__ __forceinline__ unsigned aldc(const unsigned* p) {
  return __hip_atomic_load(p, __ATOMIC_RELAXED, __HIP_MEMORY_SCOPE_AGENT);
}
__device__ __forceinline__ unsigned long long ald64(const unsigned long long* p) {
  return __hip_atomic_load(p, __ATOMIC_RELAXED, __HIP_MEMORY_SCOPE_AGENT);
}
__device__ __forceinline__ void ast32(unsigned* p, unsigned v) {
  __hip_atomic_store(p, v, __ATOMIC_RELAXED, __HIP_MEMORY_SCOPE_AGENT);
}

// Poll 32 counter lines (stride 32 u32 = 128B) until all >= target; return min.
__device__ __forceinline__ unsigned wait32min(const unsigned* base, unsigned target) {
  const int i = threadIdx.x & 31;
  unsigned v;
  while (true) {
    v = aldc(base + i * 32);
    if (__ballot(v < target) == 0ull) break;
    __builtin_amdgcn_s_sleep(4);
  }
  unsigned mn = v;
  mn = min(mn, (unsigned)__shfl_xor((int)mn, 1));
  mn = min(mn, (unsigned)__shfl_xor((int)mn, 2));
  mn = min(mn, (unsigned)__shfl_xor((int)mn, 4));
  mn = min(mn, (unsigned)__shfl_xor((int)mn, 8));
  mn = min(mn, (unsigned)__shfl_xor((int)mn, 16));
  return mn;
}
// Single-counter wait; one wave spins, the rest park on the barrier.
__device__ __forceinline__ void wait_cnt_blk(const unsigned* p, unsigned target) {
  if (threadIdx.x < 64) {
    while (aldc(p) < target) __builtin_amdgcn_s_sleep(8);
  }
  __syncthreads();
}

// ---------------------------------------------------------------------------
// Pre-conversion kernels (run once before fused_k).
// ---------------------------------------------------------------------------
__global__ __launch_bounds__(256) void split_hl_k(const float* __restrict__ s,
                                                  unsigned short* __restrict__ hi,
                                                  unsigned short* __restrict__ lo) {
  int i = (blockIdx.x * 256 + threadIdx.x) * 4;
  float4 v = *(const float4*)(s + i);
  ushort4 h, l;
  h.x = f2bf(v.x); l.x = f2bf(v.x - bf2f(h.x));
  h.y = f2bf(v.y); l.y = f2bf(v.y - bf2f(h.y));
  h.z = f2bf(v.z); l.z = f2bf(v.z - bf2f(h.z));
  h.w = f2bf(v.w); l.w = f2bf(v.w - bf2f(h.w));
  *(ushort4*)(hi + i) = h;
  *(ushort4*)(lo + i) = l;
}
__global__ __launch_bounds__(256) void cvt_hi_k(const float* __restrict__ s,
                                               unsigned short* __restrict__ hi) {
  int i = (blockIdx.x * 256 + threadIdx.x) * 4;
  float4 v = *(const float4*)(s + i);
  ushort4 h;
  h.x = f2bf(v.x); h.y = f2bf(v.y); h.z = f2bf(v.z); h.w = f2bf(v.w);
  *(ushort4*)(hi + i) = h;
}

// ---------------------------------------------------------------------------
// GEMM tiles (r7-proven math; operands pre-converted -> staging = 16B copies).
// ---------------------------------------------------------------------------
// xin tile for layers 1..3: 128 rows x 256 cols, K=1024, B hi-only.
__device__ void tile_seq(const unsigned short* __restrict__ A,
                         const unsigned short* __restrict__ Wh,
                         const float* __restrict__ b1, const float* __restrict__ b2,
                         unsigned* __restrict__ xo, int mt, int ng,
                         unsigned short* smem) {
  const int tid = threadIdx.x;
  const int wave = tid >> 6, lane = tid & 63;
  const int wm = wave >> 1, wn = wave & 1;
  const int lm = lane & 15, lk = lane >> 4;
  unsigned short* Ah = smem;          // 8192 u16
  unsigned short* Bh = smem + 8192;   // 16384 u16
  f32x4_t acc[4][8] = {};
  for (int kc = 0; kc < H_; kc += 64) {
    __syncthreads();
#pragma unroll
    for (int p = 0; p < 4; ++p) {
      int fl = p * 256 + tid;
      int row = fl & 127, ks = fl >> 7;
      int kk = kc + (ks >> 2) * 32 + (ks & 3) * 8;
      const unsigned long long* s8 =
          (const unsigned long long*)(A + (size_t)(mt * 128 + row) * H_ + kk);
      union { bf16x8_t v; unsigned long long w[2]; } tmp;
      tmp.w[0] = ald64(s8);
      tmp.w[1] = ald64(s8 + 1);
      *(bf16x8_t*)(Ah + fl * 8) = tmp.v;
    }
#pragma unroll
    for (int p = 0; p < 8; ++p) {
      int fl = p * 256 + tid;
      int col = fl & 255, ks = fl >> 8;
      int kk = kc + (ks >> 2) * 32 + (ks & 3) * 8;
      *(bf16x8_t*)(Bh + fl * 8) =
          *(const bf16x8_t*)(Wh + (size_t)(ng * 256 + col) * H_ + kk);
    }
    __syncthreads();
#pragma unroll
    for (int kit = 0; kit < 2; ++kit) {
      bf16x8_t bfr[8];
#pragma unroll
      for (int n = 0; n < 8; ++n)
        bfr[n] = *(const bf16x8_t*)(Bh + ((kit * 4 + lk) * 256 + wn * 128 + n * 16 + lm) * 8);
#pragma unroll
      for (int m = 0; m < 4; ++m) {
        bf16x8_t a = *(const bf16x8_t*)(Ah + ((kit * 4 + lk) * 128 + wm * 64 + m * 16 + lm) * 8);
#pragma unroll
        for (int n = 0; n < 8; ++n) acc[m][n] = mfma16(a, bfr[n], acc[m][n]);
      }
    }
  }
#pragma unroll
  for (int n = 0; n < 8; ++n) {
    int col = ng * 256 + wn * 128 + n * 16 + lm;
    float bv = b1[col] + b2[col];
#pragma unroll
    for (int m = 0; m < 4; ++m) {
#pragma unroll
      for (int r = 0; r < 4; ++r) {
        int row = mt * 128 + wm * 64 + m * 16 + lk * 4 + r;
        unsigned hv = f2bf(acc[m][n][r] + bv);
        unsigned ov = (unsigned)__shfl_xor((int)hv, 1);
        if (!(lm & 1)) ast32(xo + (size_t)row * (H_ / 2) + (col >> 1), hv | (ov << 16));
      }
    }
  }
}

// layer-0 input projection: A = x (pre-split hi/lo), B = Wih0 (hi/lo), K=128.
__device__ void tile_l0(const unsigned short* __restrict__ xhi,
                        const unsigned short* __restrict__ xlo, int c,
                        const unsigned short* __restrict__ w0h,
                        const unsigned short* __restrict__ w0l,
                        const float* __restrict__ b1, const float* __restrict__ b2,
                        unsigned* __restrict__ xo, int mt, int nt,
                        unsigned short* smem) {
  const int tid = threadIdx.x;
  const int wave = tid >> 6, lane = tid & 63;
  const int wm = wave >> 1, wn = wave & 1;
  const int lm = lane & 15, lk = lane >> 4;
  unsigned short* Ahi = smem;
  unsigned short* Alo = smem + 8192;
  unsigned short* Bhi = smem + 16384;
  unsigned short* Blo = smem + 24576;
  f32x4_t acc[4][4] = {};
  for (int kc = 0; kc < I_; kc += 64) {
    __syncthreads();
#pragma unroll
    for (int p = 0; p < 4; ++p) {
      int fl = p * 256 + tid;
      int row = fl & 127, ks = fl >> 7;
      int kk = kc + (ks >> 2) * 32 + (ks & 3) * 8;
      int srow = mt * 128 + row;
      int b = srow & 63, tl = srow >> 6;
      size_t off = ((size_t)b * T_ + c * S_ + tl) * I_ + kk;
      *(bf16x8_t*)(Ahi + fl * 8) = *(const bf16x8_t*)(xhi + off);
      *(bf16x8_t*)(Alo + fl * 8) = *(const bf16x8_t*)(xlo + off);
    }
#pragma unroll
    for (int p = 0; p < 4; ++p) {
      int fl = p * 256 + tid;
      int row = fl & 127, ks = fl >> 7;
      int kk = kc + (ks >> 2) * 32 + (ks & 3) * 8;
      size_t off = (size_t)(nt * 128 + row) * I_ + kk;
      *(bf16x8_t*)(Bhi + fl * 8) = *(const bf16x8_t*)(w0h + off);
      *(bf16x8_t*)(Blo + fl * 8) = *(const bf16x8_t*)(w0l + off);
    }
    __syncthreads();
#pragma unroll
    for (int kit = 0; kit < 2; ++kit) {
      bf16x8_t bhf[4], blf[4];
#pragma unroll
      for (int n = 0; n < 4; ++n) {
        int off = ((kit * 4 + lk) * 128 + wn * 64 + n * 16 + lm) * 8;
        bhf[n] = *(const bf16x8_t*)(Bhi + off);
        blf[n] = *(const bf16x8_t*)(Blo + off);
      }
#pragma unroll
      for (int m = 0; m < 4; ++m) {
        int off = ((kit * 4 + lk) * 128 + wm * 64 + m * 16 + lm) * 8;
        bf16x8_t a = *(const bf16x8_t*)(Ahi + off);
        bf16x8_t al = *(const bf16x8_t*)(Alo + off);
#pragma unroll
        for (int n = 0; n < 4; ++n) {
          acc[m][n] = mfma16(a, bhf[n], acc[m][n]);
          acc[m][n] = mfma16(a, blf[n], acc[m][n]);
          acc[m][n] = mfma16(al, bhf[n], acc[m][n]);
        }
      }
    }
  }
#pragma unroll
  for (int n = 0; n < 4; ++n) {
    int col = nt * 128 + wn * 64 + n * 16 + lm;
    float bv = b1[col] + b2[col];
#pragma unroll
    for (int m = 0; m < 4; ++m) {
#pragma unroll
      for (int r = 0; r < 4; ++r) {
        int row = mt * 128 + wm * 64 + m * 16 + lk * 4 + r;
        unsigned hv = f2bf(acc[m][n][r] + bv);
        unsigned ov = (unsigned)__shfl_xor((int)hv, 1);
        if (!(lm & 1)) ast32(xo + (size_t)row * (H_ / 2) + (col >> 1), hv | (ov << 16));
      }
    }
  }
}

// FC tile: A = seqr l3 chunk (u16 sc1), B = Wfc (pre-split hi/lo), out fp32.
__device__ void tile_fc(const unsigned short* __restrict__ A,
                        const unsigned short* __restrict__ wfch,
                        const unsigned short* __restrict__ wfcl,
                        const float* __restrict__ bfc,
                        float* __restrict__ out, int c, int mt,
                        unsigned short* smem) {
  const int tid = threadIdx.x;
  const int wave = tid >> 6, lane = tid & 63;
  const int wm = wave >> 1, wn = wave & 1;
  const int lm = lane & 15, lk = lane >> 4;
  unsigned short* Ah = smem;
  unsigned short* Bhi = smem + 8192;
  unsigned short* Blo = smem + 16384;
  f32x4_t acc[4][4] = {};
  for (int kc = 0; kc < H_; kc += 64) {
    __syncthreads();
#pragma unroll
    for (int p = 0; p < 4; ++p) {
      int fl = p * 256 + tid;
      int row = fl & 127, ks = fl >> 7;
      int kk = kc + (ks >> 2) * 32 + (ks & 3) * 8;
      const unsigned long long* s8 =
          (const unsigned long long*)(A + (size_t)(mt * 128 + row) * H_ + kk);
      union { bf16x8_t v; unsigned long long w[2]; } tmp;
      tmp.w[0] = ald64(s8);
      tmp.w[1] = ald64(s8 + 1);
      *(bf16x8_t*)(Ah + fl * 8) = tmp.v;
    }
#pragma unroll
    for (int p = 0; p < 4; ++p) {
      int fl = p * 256 + tid;
      int col = fl & 127, ks = fl >> 7;
      int kk = kc + (ks >> 2) * 32 + (ks & 3) * 8;
      size_t off = (size_t)col * H_ + kk;
      *(bf16x8_t*)(Bhi + fl * 8) = *(const bf16x8_t*)(wfch + off);
      *(bf16x8_t*)(Blo + fl * 8) = *(const bf16x8_t*)(wfcl + off);
    }
    __syncthreads();
#pragma unroll
    for (int kit = 0; kit < 2; ++kit) {
      bf16x8_t bhf[4], blf[4];
#pragma unroll
      for (int n = 0; n < 4; ++n) {
        int off = ((kit * 4 + lk) * 128 + wn * 64 + n * 16 + lm) * 8;
        bhf[n] = *(const bf16x8_t*)(Bhi + off);
        blf[n] = *(const bf16x8_t*)(Blo + off);
      }
#pragma unroll
      for (int m = 0; m < 4; ++m) {
        bf16x8_t a = *(const bf16x8_t*)(Ah + ((kit * 4 + lk) * 128 + wm * 64 + m * 16 + lm) * 8);
#pragma unroll
        for (int n = 0; n < 4; ++n) {
          acc[m][n] = mfma16(a, bhf[n], acc[m][n]);
          acc[m][n] = mfma16(a, blf[n], acc[m][n]);
        }
      }
    }
  }
#pragma unroll
  for (int n = 0; n < 4; ++n) {
    int col = wn * 64 + n * 16 + lm;
    float bv = bfc[col];
#pragma unroll
    for (int m = 0; m < 4; ++m) {
#pragma unroll
      for (int r = 0; r < 4; ++r) {
        int srow = mt * 128 + wm * 64 + m * 16 + lk * 4 + r;
        int b = srow & 63, tl = srow >> 6;
        out[((size_t)b * T_ + c * S_ + tl) * O_ + col] = acc[m][n][r] + bv;
      }
    }
  }
}

// ---------------------------------------------------------------------------
// Fused persistent kernel. Roles:
//   bid 0..127   rec: l=bid>>5, bg=(bid>>3)&3 (16 batches), me=bid&7 (128 neurons)
//   bid 128..159 l0 xin (2 tiles/chunk each; 64 total)
//   bid 160..231 l1..3 xin (24 blocks/layer; 32 tiles/chunk/layer)
//   bid 232..239 FC (1 tile/chunk each; 8 total)
// ---------------------------------------------------------------------------
__global__ __launch_bounds__(256, 1) void fused_k(
    const float* __restrict__ hidden,
    const float* __restrict__ Whh0, const float* __restrict__ WhhL,
    const float* __restrict__ bih0, const float* __restrict__ bhh0,
    const float* __restrict__ bihL, const float* __restrict__ bhhL,
    const float* __restrict__ bfc,
    const unsigned short* __restrict__ xhi, const unsigned short* __restrict__ xlo,
    const unsigned short* __restrict__ w0h, const unsigned short* __restrict__ w0l,
    const unsigned short* __restrict__ wihh,
    const unsigned short* __restrict__ wfch, const unsigned short* __restrict__ wfcl,
    float* __restrict__ out, float* __restrict__ hn,
    unsigned* __restrict__ rprog, unsigned* __restrict__ gchunk,
    unsigned* __restrict__ gfc,
    unsigned* __restrict__ ring, unsigned short* __restrict__ xin,
    unsigned short* __restrict__ seqr) {
  extern __shared__ char lds[];
  const int tid = threadIdx.x;
  const int wave = tid >> 6, lane = tid & 63;
  const int lm = lane & 15, lk = lane >> 4;
  const int bid = blockIdx.x;

  if (bid < 128) {
    // ===================== recurrence role =====================
    const int l = bid >> 5, sub = bid & 31, bg = sub >> 3, me = sub & 7;
    const int j0 = me * 128 + wave * 32;

    const float* Whh = (l == 0) ? Whh0 : WhhL + (size_t)(l - 1) * H_ * H_;
    bf16x8_t bh0[32], bh1[32];
#pragma unroll
    for (int kit = 0; kit < 32; ++kit) {
      const float* s0 = Whh + (size_t)(j0 + lm) * H_ + kit * 32 + lk * 8;
      const float* s1 = Whh + (size_t)(j0 + 16 + lm) * H_ + kit * 32 + lk * 8;
      union { bf16x8_t s; unsigned short u[8]; } t0, t1;
#pragma unroll
      for (int e = 0; e < 8; ++e) {
        t0.u[e] = (short)f2bf(s0[e]);
        t1.u[e] = (short)f2bf(s1[e]);
      }
      bh0[kit] = t0.s;
      bh1[kit] = t1.s;
    }

    // init h0 -> ring slot 1 (block's 128-neuron x 16-batch slice; 1024 u32)
    {
      unsigned* r1 = ring + ((size_t)((l * 4 + bg) * 2 + 1)) * 8192;
#pragma unroll
      for (int q = 0; q < 4; ++q) {
        int idx = q * 256 + tid;
        int jo = idx >> 6, rem = idx & 63;
        int b16 = rem >> 2, jp = rem & 3;
        int j = me * 128 + jo * 8 + jp * 2;
        const float* hp = hidden + (size_t)l * B_ * H_ + (bg * 16 + b16) * H_ + j;
        ast32(r1 + me * 1024 + idx, (unsigned)f2bf(hp[0]) | ((unsigned)f2bf(hp[1]) << 16));
      }
    }
    __syncthreads();  // drains vmcnt -> release
    unsigned* myline = rprog + ((size_t)((l * 4 + bg) * 8 + me)) * 32;
    if (tid == 0) ast32(myline, 1u);
    const unsigned* ownB = rprog + (size_t)(l * 4 + bg) * 8 * 32;

    for (int t = 0; t < T_; ++t) {
      const int c = t >> 4;
      if ((t & 15) == 0) {
        wait_cnt_blk(gchunk + (size_t)(l * NCH + c) * 32, l == 0 ? 64u : 32u);
        if (c >= 4) {
          if (l < 3) wait_cnt_blk(gchunk + (size_t)((l + 1) * NCH + (c - 4)) * 32, 32u);
          else       wait_cnt_blk(gfc + (size_t)(c - 4) * 32, 8u);
        }
      }
      // xin loads (depend only on the chunk wait)
      const unsigned* xb = (const unsigned*)xin + (size_t)(l * 2 + (c & 1)) * (ROWS * H_ / 2);
      unsigned xv[2][4];
#pragma unroll
      for (int n = 0; n < 2; ++n)
#pragma unroll
        for (int r = 0; r < 4; ++r) {
          int b = bg * 16 + lk * 4 + r;
          int row = (t & 15) * 64 + b;
          int j = j0 + n * 16 + lm;
          xv[n][r] = aldc(xb + (size_t)row * (H_ / 2) + (j >> 1));
        }
      // own-group barrier: all 8 members finished step t-1
      {
        const int i = tid & 7;
        while (true) {
          unsigned v = aldc(ownB + i * 32);
          if (__ballot(v < (unsigned)(t + 1)) == 0ull) break;
          __builtin_amdgcn_s_sleep(1);
        }
      }
      // h slice (32 KB = 8192 u32) -> LDS
      {
        const unsigned long long* hp64 = (const unsigned long long*)(
            ring + ((size_t)((l * 4 + bg) * 2 + ((t & 1) ^ 1))) * 8192);
        unsigned long long ht[16];
#pragma unroll
        for (int i = 0; i < 16; ++i) ht[i] = ald64(hp64 + i * 256 + tid);
#pragma unroll
        for (int i = 0; i < 16; ++i)
          ((unsigned long long*)lds)[i * 256 + tid] = ht[i];
      }
      __syncthreads();
      // MFMA: 4 independent chains (2 n-tiles x even/odd kit)
      f32x4_t a0e = {0.f, 0.f, 0.f, 0.f}, a0o = a0e, a1e = a0e, a1o = a0e;
#pragma unroll
      for (int kit = 0; kit < 32; kit += 2) {
        bf16x8_t aA = *(const bf16x8_t*)(lds + (size_t)((kit * 4 + lk) * 16 + lm) * 16);
        bf16x8_t aB = *(const bf16x8_t*)(lds + (size_t)(((kit + 1) * 4 + lk) * 16 + lm) * 16);
        a0e = mfma16(aA, bh0[kit], a0e);
        a1e = mfma16(aA, bh1[kit], a1e);
        a0o = mfma16(aB, bh0[kit + 1], a0o);
        a1o = mfma16(aB, bh1[kit + 1], a1o);
      }
      // epilogue: lane holds (neuron j via lm, batch b16 = lk*4+r)
      unsigned* rw = ring + ((size_t)((l * 4 + bg) * 2 + (t & 1))) * 8192;
      unsigned* sw = (unsigned*)(seqr + (size_t)(l * 4 + (c & 3)) * (ROWS * H_));
      const bool evenl = !(lm & 1);
#pragma unroll
      for (int r = 0; r < 4; ++r) {
        const int b16 = lk * 4 + r;
        const int b = bg * 16 + b16;
        const int row = (t & 15) * 64 + b;
        float v0 = a0e[r] + a0o[r] + bf2f((unsigned short)(xv[0][r] >> ((lm & 1) * 16)));
        float v1 = a1e[r] + a1o[r] + bf2f((unsigned short)(xv[1][r] >> ((lm & 1) * 16)));
        v0 = fmaxf(v0, 0.f);
        v1 = fmaxf(v1, 0.f);
        unsigned h0v = f2bf(v0), h1v = f2bf(v1);
        unsigned o0 = (unsigned)__shfl_xor((int)h0v, 1);
        unsigned o1 = (unsigned)__shfl_xor((int)h1v, 1);
        if (evenl) {
          int j = j0 + lm;  // even
          unsigned pk = h0v | (o0 << 16);
          ast32(rw + ((j >> 3) * 16 + b16) * 4 + ((j & 7) >> 1), pk);
          ast32(sw + (size_t)row * (H_ / 2) + (j >> 1), pk);
        } else {
          int j = j0 + 16 + lm;  // odd
          int ja = j & ~1;
          unsigned pk = o1 | (h1v << 16);
          ast32(rw + ((ja >> 3) * 16 + b16) * 4 + ((ja & 7) >> 1), pk);
          ast32(sw + (size_t)row * (H_ / 2) + (ja >> 1), pk);
        }
        if (t == T_ - 1) {
          hn[(size_t)l * B_ * H_ + (size_t)b * H_ + (j0 + lm)] = v0;
          hn[(size_t)l * B_ * H_ + (size_t)b * H_ + (j0 + 16 + lm)] = v1;
        }
      }
      __syncthreads();  // drains all waves' stores -> release
      if (tid == 0) ast32(myline, (unsigned)(t + 2));
    }
  } else if (bid < 160) {
    // ===================== l0 xin role: 32 blocks, 2 tiles/chunk ===========
    const int idx = bid - 128;
    unsigned short* smem = (unsigned short*)lds;
    unsigned minRec = 0u;
    for (int c = 0; c < NCH; ++c) {
      if (c >= 2) {  // WAR: rec[0] finished chunk c-2 (read xin slot c&1)
        unsigned bp = (unsigned)(16 * c - 15);
        if (minRec < bp) minRec = wait32min(rprog, bp);
      }
      unsigned* xo = (unsigned*)(xin + (size_t)(c & 1) * (ROWS * H_));
#pragma unroll
      for (int q = 0; q < 2; ++q) {
        int v = idx * 2 + q;
        tile_l0(xhi, xlo, c, w0h, w0l, bih0, bhh0, xo, v >> 3, v & 7, smem);
      }
      __syncthreads();
      if (tid == 0)
        __hip_atomic_fetch_add(gchunk + (size_t)c * 32, 2u,
                               __ATOMIC_RELAXED, __HIP_MEMORY_SCOPE_AGENT);
    }
  } else if (bid < 232) {
    // ===================== l1..3 xin role: 24 blocks/layer =================
    const int l = 1 + (bid - 160) / 24;
    const int idx = (bid - 160) % 24;
    unsigned short* smem = (unsigned short*)lds;
    unsigned minUp = 0u, minOwn = 0u;
    const unsigned short* Wh = wihh + (size_t)(l - 1) * H_ * H_;
    const float* b1 = bihL + (size_t)(l - 1) * H_;
    const float* b2 = bhhL + (size_t)(l - 1) * H_;
    for (int c = 0; c < NCH; ++c) {
      unsigned tgt = (unsigned)(16 * c + 17);  // RAW: rec[l-1] finished chunk c
      if (minUp < tgt) minUp = wait32min(rprog + (size_t)(l - 1) * 1024, tgt);
      if (c >= 2) {  // WAR: rec[l] finished chunk c-2
        unsigned bp = (unsigned)(16 * c - 15);
        if (minOwn < bp) minOwn = wait32min(rprog + (size_t)l * 1024, bp);
      }
      const unsigned short* A = seqr + (size_t)((l - 1) * 4 + (c & 3)) * (ROWS * H_);
      unsigned* xo = (unsigned*)(xin + (size_t)(l * 2 + (c & 1)) * (ROWS * H_));
      unsigned cnt = 0;
      for (int w = idx; w < 32; w += 24) {
        tile_seq(A, Wh, b1, b2, xo, w >> 2, w & 3, smem);
        ++cnt;
      }
      __syncthreads();
      if (tid == 0)
        __hip_atomic_fetch_add(gchunk + (size_t)(l * NCH + c) * 32, cnt,
                               __ATOMIC_RELAXED, __HIP_MEMORY_SCOPE_AGENT);
    }
  } else {
    // ===================== FC role: 8 blocks ===============================
    const int mt = bid - 232;
    unsigned short* smem = (unsigned short*)lds;
    unsigned minRec3 = 0u;
    for (int c = 0; c < NCH; ++c) {
      unsigned tgt = (unsigned)(16 * c + 17);
      if (minRec3 < tgt) minRec3 = wait32min(rprog + (size_t)3 * 1024, tgt);
      const unsigned short* A = seqr + (size_t)(3 * 4 + (c & 3)) * (ROWS * H_);
      tile_fc(A, wfch, wfcl, bfc, out, c, mt, smem);
      __syncthreads();
      if (tid == 0)
        __hip_atomic_fetch_add(gfc + (size_t)c * 32, 1u,
                               __ATOMIC_RELAXED, __HIP_MEMORY_SCOPE_AGENT);
    }
  }
}

// ---------------------------------------------------------------------------
// ws layout (bytes):
//   0       rprog  (128 lines x 128 B = 16 KB)
//   16384   gchunk (128 lines x 128 B = 16 KB)
//   32768   gfc    (32 lines x 128 B = 4 KB)
//   65536   ring   (16 groups x 2 slots x 8192 u32 = 1 MB)
//   +1MB    xin    (4l x 2slot x ROWS x H u16 = 16 MB)
//   +16MB   seqr   (4l x 4slot x ROWS x H u16 = 32 MB)
//   +32MB   xhi 8MB | xlo 8MB | wihh 6MB | w0h/w0l/wfch/wfcl 256KB each
// total ~72.3 MB.
// ---------------------------------------------------------------------------
extern "C" void kernel_launch(void* const* d_in, const int* in_sizes, int n_in,
                              void* d_out, int out_size, void* d_ws, size_t ws_size,
                              hipStream_t stream) {
  const float* x = (const float*)d_in[0];
  const float* hidden = (const float*)d_in[1];
  const float* Wih0 = (const float*)d_in[2];
  const float* Whh0 = (const float*)d_in[3];
  const float* bih0 = (const float*)d_in[4];
  const float* bhh0 = (const float*)d_in[5];
  const float* WihL = (const float*)d_in[6];
  const float* WhhL = (const float*)d_in[7];
  const float* bihL = (const float*)d_in[8];
  const float* bhhL = (const float*)d_in[9];
  const float* Wfc = (const float*)d_in[10];
  const float* bfc = (const float*)d_in[11];
  float* out = (float*)d_out;
  float* hn = out + (size_t)M_ * O_;

  char* ws = (char*)d_ws;
  unsigned* rprog = (unsigned*)ws;
  unsigned* gchunk = (unsigned*)(ws + 16384);
  unsigned* gfc = (unsigned*)(ws + 32768);
  unsigned* ring = (unsigned*)(ws + 65536);
  unsigned short* xin = (unsigned short*)(ws + 65536 + (1u << 20));
  unsigned short* seqr = xin + (size_t)8 * 1024 * 1024;
  unsigned short* xhi = seqr + (size_t)16 * 1024 * 1024;
  unsigned short* xlo = xhi + (size_t)4 * 1024 * 1024;
  unsigned short* wihh = xlo + (size_t)4 * 1024 * 1024;
  unsigned short* w0h = wihh + (size_t)3 * 1024 * 1024;
  unsigned short* w0l = w0h + 131072;
  unsigned short* wfch = w0l + 131072;
  unsigned short* wfcl = wfch + 131072;

  hipMemsetAsync(ws, 0, 65536, stream);  // all progress counters

  split_hl_k<<<4096, 256, 0, stream>>>(x, xhi, xlo);       // B*T*I = 4M elems
  split_hl_k<<<128, 256, 0, stream>>>(Wih0, w0h, w0l);     // 131072
  split_hl_k<<<128, 256, 0, stream>>>(Wfc, wfch, wfcl);    // 131072
  cvt_hi_k<<<3072, 256, 0, stream>>>(WihL, wihh);          // 3M elems

  hipFuncSetAttribute((const void*)fused_k, hipFuncAttributeMaxDynamicSharedMemorySize,
                      64 * 1024);
  fused_k<<<240, 256, 64 * 1024, stream>>>(hidden, Whh0, WhhL, bih0, bhh0,
                                           bihL, bhhL, bfc, xhi, xlo, w0h, w0l,
                                           wihh, wfch, wfcl, out, hn,
                                           rprog, gchunk, gfc, ring, xin, seqr);
}